// Round 8
// baseline (182.044 us; speedup 1.0000x reference)
//
#include <hip/hip_runtime.h>
#include <hip/hip_bf16.h>
#include <stdint.h>

typedef short bf16x8 __attribute__((ext_vector_type(8)));
typedef float f32x4 __attribute__((ext_vector_type(4)));

__device__ __forceinline__ float b2f(unsigned short u) {
    union { unsigned int i; float f; } c; c.i = ((unsigned int)u) << 16; return c.f;
}
__device__ __forceinline__ unsigned short f2b(float f) {
    union { float f; unsigned int i; } c; c.f = f;
    unsigned int u = c.i;
    u += 0x7fffu + ((u >> 16) & 1u);   // round-to-nearest-even
    return (unsigned short)(u >> 16);
}

__device__ __forceinline__ void gload_lds16(const void* g, void* l) {
    __builtin_amdgcn_global_load_lds(
        (const __attribute__((address_space(1))) void*)g,
        (__attribute__((address_space(3))) void*)l, 16, 0, 0);
}

// ---------------- fused f32 -> bf16 convert: x + Wq + Wk + Wv in one launch ----------------
__global__ __launch_bounds__(256) void convert_all(const float* __restrict__ x,
                                                   const float* __restrict__ Wq,
                                                   const float* __restrict__ Wk,
                                                   const float* __restrict__ Wv,
                                                   unsigned short* __restrict__ xb,
                                                   unsigned short* __restrict__ wb) {
    const long X4 = 2097152, W4 = 262144, TOT = X4 + 3 * W4;
    long i = (long)blockIdx.x * blockDim.x + threadIdx.x;
    long stride = (long)gridDim.x * blockDim.x;
    for (; i < TOT; i += stride) {
        const float4* src;
        ushort4* dst;
        if (i < X4) {
            src = (const float4*)x + i;
            dst = (ushort4*)xb + i;
        } else {
            long j = i - X4;
            int w = (int)(j >> 18);          // 262144 = 2^18
            long off = j & (W4 - 1);
            const float* s = (w == 0) ? Wq : (w == 1) ? Wk : Wv;
            src = (const float4*)s + off;
            dst = (ushort4*)wb + (long)w * W4 + off;
        }
        float4 v = *src;
        ushort4 o;
        o.x = f2b(v.x); o.y = f2b(v.y); o.z = f2b(v.z); o.w = f2b(v.w);
        *dst = o;
    }
}

// ---------------- per-row 1/sum reduce: linv[r] = 1 / sum_i lp[i][r] ----------------
__global__ __launch_bounds__(256) void row_linv(const float* __restrict__ lp,
                                                float* __restrict__ linv) {
    int r = blockIdx.x * 256 + threadIdx.x;   // 0..8191 = b*2048 + q
    int q = r & 2047;
    int ns = ((q >> 7) + 1) * 2;
    float s = 0.f;
    for (int i = 0; i < ns; i++) s += lp[i * 8192 + r];
    linv[r] = 1.f / s;
}

#define BM 128
#define BN 128
#define BK 64

// ---------------- bf16 GEMM-BT:  C[m][n] = sum_k A[m][k] * B[n][k] ----------------
// MODE 0: Q/K projection only (grid.x = 16). C0=Q (scaled 1/32), C1=K.
// MODE 1: scores. P_unnorm = exp(score) bf16 masked, row partial sums -> lp (C1).
// MODE 2: PV. f32 out scaled by linv[row] (C1), K_eff = min(K, m0+BM), pair-balanced mb.
template <int MODE>
__global__ __launch_bounds__(256)
void gemm_bt(const unsigned short* __restrict__ A, const unsigned short* __restrict__ B,
             void* __restrict__ C0, void* __restrict__ C1, void* __restrict__ C2,
             int M, int N, int K,
             long sA, long sB, long sC, int lda, int ldb, int ldc) {
    int mb, nb;
    if (MODE == 1) {
        // compact lower-triangular decode
        int l = blockIdx.x;
        mb = (int)((sqrtf(8.f * l + 1.f) - 1.f) * 0.5f);
        while ((mb + 1) * (mb + 2) / 2 <= l) mb++;
        while (mb * (mb + 1) / 2 > l) mb--;
        nb = l - mb * (mb + 1) / 2;
    } else if (MODE == 2) {
        // pair-balanced: block b and b+256 (same CU) get mb summing to 15
        mb = (blockIdx.z & 2) ? (gridDim.y - 1 - blockIdx.y) : blockIdx.y;
        nb = blockIdx.x;
    } else {
        mb = blockIdx.y;
        nb = blockIdx.x;
    }
    int bz = blockIdx.z;

    __shared__ unsigned short As[BM * BK];
    __shared__ unsigned short Bs[BN * BK];

    const unsigned short* Ab = A + (long)bz * sA;
    const unsigned short* Bb = B + (long)bz * sB;

    const int t = threadIdx.x;
    const int lane = t & 63;
    const int wid = t >> 6;
    const int wr = wid >> 1, wc = wid & 1;
    const int m0 = mb * BM, n0 = nb * BN;

    int Keff = K;
    if (MODE == 2) Keff = min(K, m0 + BM);

    f32x4 acc[4][4];
    #pragma unroll
    for (int i = 0; i < 4; i++)
        #pragma unroll
        for (int j = 0; j < 4; j++) acc[i][j] = (f32x4){0.f, 0.f, 0.f, 0.f};

    // staging map: 16B chunk u = i*256+t; row = u>>3; lds chunk = u&7;
    // source chunk = (u&7) ^ (row&7)  (inverse-XOR-swizzled global source, linear LDS dest)
    int rowS[4], csrc[4];
    #pragma unroll
    for (int i = 0; i < 4; i++) {
        int u = i * 256 + t;
        rowS[i] = u >> 3;
        csrc[i] = (u & 7) ^ (rowS[i] & 7);
    }

    for (int k0 = 0; k0 < Keff; k0 += BK) {
        __syncthreads();   // previous compute done before overwrite
        #pragma unroll
        for (int i = 0; i < 4; i++) {
            const unsigned short* gp = Ab + (long)(m0 + rowS[i]) * lda + k0 + csrc[i] * 8;
            gload_lds16(gp, (void*)&As[(i * 256 + wid * 64) * 8]);
        }
        #pragma unroll
        for (int i = 0; i < 4; i++) {
            const unsigned short* gp = Bb + (long)(n0 + rowS[i]) * ldb + k0 + csrc[i] * 8;
            gload_lds16(gp, (void*)&Bs[(i * 256 + wid * 64) * 8]);
        }
        asm volatile("s_waitcnt vmcnt(0)" ::: "memory");
        __syncthreads();

        #pragma unroll
        for (int s = 0; s < 2; s++) {      // two K=32 slices per BK=64
            bf16x8 af[4], bfr[4];
            int kc = s * 4 + (lane >> 4);  // 16B chunk within row
            #pragma unroll
            for (int m = 0; m < 4; m++) {
                int r = wr * 64 + m * 16 + (lane & 15);
                int c = kc ^ (r & 7);
                af[m] = *(const bf16x8*)&As[r * BK + c * 8];
            }
            #pragma unroll
            for (int n = 0; n < 4; n++) {
                int r = wc * 64 + n * 16 + (lane & 15);
                int c = kc ^ (r & 7);
                bfr[n] = *(const bf16x8*)&Bs[r * BK + c * 8];
            }
            #pragma unroll
            for (int m = 0; m < 4; m++)
                #pragma unroll
                for (int n = 0; n < 4; n++)
                    acc[m][n] = __builtin_amdgcn_mfma_f32_16x16x32_bf16(af[m], bfr[n], acc[m][n], 0, 0, 0);
        }
    }

    // epilogue: C/D layout col=lane&15, row=(lane>>4)*4+reg
    const int r0 = (lane >> 4) * 4;
    const int cf = lane & 15;
    if (MODE == 0) {
        int buf = n0 >> 10;  // 0 = Q, 1 = K (grid.x = 16 => only these)
        unsigned short* Cb = (unsigned short*)(buf == 0 ? C0 : C1);
        float scale = (buf == 0) ? 0.03125f : 1.0f;  // fold 1/sqrt(1024) into Q
        #pragma unroll
        for (int m = 0; m < 4; m++)
            #pragma unroll
            for (int n = 0; n < 4; n++)
                #pragma unroll
                for (int r = 0; r < 4; r++) {
                    long grow = m0 + wr * 64 + m * 16 + r0 + r;
                    int gcol = (n0 & 1023) + wc * 64 + n * 16 + cf;
                    Cb[grow * 1024 + gcol] = f2b(acc[m][n][r] * scale);
                }
    } else if (MODE == 1) {
        // fused exp + causal mask + per-row partial sums
        unsigned short* Cb = (unsigned short*)C0 + (long)bz * sC;
        float* lp = (float*)C1;   // [32][8192]
        float srow[4][4];
        #pragma unroll
        for (int m = 0; m < 4; m++)
            #pragma unroll
            for (int r = 0; r < 4; r++) srow[m][r] = 0.f;
        #pragma unroll
        for (int m = 0; m < 4; m++)
            #pragma unroll
            for (int n = 0; n < 4; n++)
                #pragma unroll
                for (int r = 0; r < 4; r++) {
                    int grow = m0 + wr * 64 + m * 16 + r0 + r;
                    int gcol = n0 + wc * 64 + n * 16 + cf;
                    float e = (gcol <= grow) ? __expf(acc[m][n][r]) : 0.f;
                    srow[m][r] += e;
                    Cb[(long)grow * ldc + gcol] = f2b(e);
                }
        #pragma unroll
        for (int m = 0; m < 4; m++)
            #pragma unroll
            for (int r = 0; r < 4; r++) {
                float s = srow[m][r];
                s += __shfl_xor(s, 1);
                s += __shfl_xor(s, 2);
                s += __shfl_xor(s, 4);
                s += __shfl_xor(s, 8);
                if ((lane & 15) == 0) {
                    int grow = m0 + wr * 64 + m * 16 + r0 + r;
                    lp[(nb * 2 + wc) * 8192 + bz * 2048 + grow] = s;
                }
            }
    } else {
        float* Cb = (float*)C0 + (long)bz * sC;
        const float* linv = (const float*)C1;   // [4][2048]
        #pragma unroll
        for (int m = 0; m < 4; m++)
            #pragma unroll
            for (int r = 0; r < 4; r++) {
                long grow = m0 + wr * 64 + m * 16 + r0 + r;
                float sc = linv[bz * 2048 + grow];
                #pragma unroll
                for (int n = 0; n < 4; n++) {
                    int gcol = n0 + wc * 64 + n * 16 + cf;
                    Cb[grow * ldc + gcol] = acc[m][n][r] * sc;
                }
            }
    }
}

// ---------------- V projection with fused transpose: Vt[b][1024][2048] ----------------
// Dedicated kernel so its codegen (merged LDS + bounce epilogue) can't perturb gemm_bt.
__global__ __launch_bounds__(256)
void gemm_vt(const unsigned short* __restrict__ A, const unsigned short* __restrict__ B,
             unsigned short* __restrict__ Vt) {
    __shared__ unsigned short As[BM * BK + BN * BK];
    unsigned short* Bs = As + BM * BK;

    const int t = threadIdx.x;
    const int lane = t & 63;
    const int wid = t >> 6;
    const int wr = wid >> 1, wc = wid & 1;
    const int m0 = blockIdx.y * BM;         // 0..8191 (b*2048 + s)
    const int n0 = blockIdx.x * BN;         // 0..1023 (d)

    f32x4 acc[4][4];
    #pragma unroll
    for (int i = 0; i < 4; i++)
        #pragma unroll
        for (int j = 0; j < 4; j++) acc[i][j] = (f32x4){0.f, 0.f, 0.f, 0.f};

    int rowS[4], csrc[4];
    #pragma unroll
    for (int i = 0; i < 4; i++) {
        int u = i * 256 + t;
        rowS[i] = u >> 3;
        csrc[i] = (u & 7) ^ (rowS[i] & 7);
    }

    for (int k0 = 0; k0 < 1024; k0 += BK) {
        __syncthreads();
        #pragma unroll
        for (int i = 0; i < 4; i++)
            gload_lds16(A + (long)(m0 + rowS[i]) * 1024 + k0 + csrc[i] * 8,
                        (void*)&As[(i * 256 + wid * 64) * 8]);
        #pragma unroll
        for (int i = 0; i < 4; i++)
            gload_lds16(B + (long)(n0 + rowS[i]) * 1024 + k0 + csrc[i] * 8,
                        (void*)&Bs[(i * 256 + wid * 64) * 8]);
        asm volatile("s_waitcnt vmcnt(0)" ::: "memory");
        __syncthreads();

        #pragma unroll
        for (int s = 0; s < 2; s++) {
            bf16x8 af[4], bfr[4];
            int kc = s * 4 + (lane >> 4);
            #pragma unroll
            for (int m = 0; m < 4; m++) {
                int r = wr * 64 + m * 16 + (lane & 15);
                int c = kc ^ (r & 7);
                af[m] = *(const bf16x8*)&As[r * BK + c * 8];
            }
            #pragma unroll
            for (int n = 0; n < 4; n++) {
                int r = wc * 64 + n * 16 + (lane & 15);
                int c = kc ^ (r & 7);
                bfr[n] = *(const bf16x8*)&Bs[r * BK + c * 8];
            }
            #pragma unroll
            for (int m = 0; m < 4; m++)
                #pragma unroll
                for (int n = 0; n < 4; n++)
                    acc[m][n] = __builtin_amdgcn_mfma_f32_16x16x32_bf16(af[m], bfr[n], acc[m][n], 0, 0, 0);
        }
    }

    // transpose epilogue via per-wave 64x64 LDS bounce (verified R7)
    const int r0 = (lane >> 4) * 4;
    const int cf = lane & 15;
    __syncthreads();   // all waves done with staging reads
    unsigned short* tw = As + wid * 4096;   // 4 waves x 8 KB
    #pragma unroll
    for (int m = 0; m < 4; m++)
        #pragma unroll
        for (int n = 0; n < 4; n++) {
            int dl = n * 16 + cf;                 // d_local 0..63
            int swz = (dl & 7) << 3;
            #pragma unroll
            for (int rp = 0; rp < 2; rp++) {
                int sl = m * 16 + r0 + rp * 2;
                unsigned int pk = (unsigned int)f2b(acc[m][n][rp * 2]) |
                                  ((unsigned int)f2b(acc[m][n][rp * 2 + 1]) << 16);
                *(unsigned int*)&tw[dl * 64 + (sl ^ swz)] = pk;
            }
        }
    long vbase = ((long)(m0 >> 11) * 1024 + n0 + wc * 64) * 2048 + (m0 & 2047) + wr * 64;
    #pragma unroll
    for (int pass = 0; pass < 4; pass++) {
        int rr = (lane >> 2) + pass * 16;     // d_local
        int c8 = (lane & 3) * 16;             // s chunk base
        int swz = (rr & 7) << 3;
        bf16x8 v0 = *(const bf16x8*)&tw[rr * 64 + (c8 ^ swz)];
        bf16x8 v1 = *(const bf16x8*)&tw[rr * 64 + ((c8 + 8) ^ swz)];
        *(bf16x8*)&Vt[vbase + (long)rr * 2048 + c8] = v0;
        *(bf16x8*)&Vt[vbase + (long)rr * 2048 + c8 + 8] = v1;
    }
}

extern "C" void kernel_launch(void* const* d_in, const int* in_sizes, int n_in,
                              void* d_out, int out_size, void* d_ws, size_t ws_size,
                              hipStream_t stream) {
    const float* x  = (const float*)d_in[0];
    const float* Wq = (const float*)d_in[1];
    const float* Wk = (const float*)d_in[2];
    const float* Wv = (const float*)d_in[3];

    // B=4, S=2048, D=1024. Workspace layout (bytes):
    char* ws = (char*)d_ws;
    unsigned short* xb = (unsigned short*)(ws);                    // 16 MB  [8192][1024]
    unsigned short* wb = (unsigned short*)(ws + 16777216);         // 6 MB   [3072][1024]
    unsigned short* Qb = (unsigned short*)(ws + 23068672);         // 16 MB  [8192][1024] (pre-scaled)
    unsigned short* Kb = (unsigned short*)(ws + 39845888);         // 16 MB
    unsigned short* Vt = (unsigned short*)(ws + 73400320);         // 16 MB  [b][1024][2048] (direct)
    unsigned short* Sb = (unsigned short*)(ws + 90177536);         // 32 MB  [b][2048][2048]
    float* lp   = (float*)(ws);                                    // 1 MB   [32][8192] (xb dead after proj)
    float* linv = (float*)(ws + 1048576);                          // 32 KB  [4][2048]

    // 1) convert everything to bf16 in one launch
    convert_all<<<dim3(2048), dim3(256), 0, stream>>>(x, Wq, Wk, Wv, xb, wb);

    // 2a) Q/K projection: [8192,1024] x [2048,1024]^T (clean R4 codegen)
    gemm_bt<0><<<dim3(16, 64, 1), 256, 0, stream>>>(
        xb, wb, Qb, Kb, nullptr, 8192, 2048, 1024, 0L, 0L, 0L, 1024, 1024, 1024);

    // 2b) V projection + fused transpose (isolated codegen)
    gemm_vt<<<dim3(8, 64), 256, 0, stream>>>(xb, wb + 2097152, Vt);

    // 3) P_unnorm = exp(Qs @ K^T) per batch, causal-masked, + row partial sums -> lp
    gemm_bt<1><<<dim3(136, 1, 4), 256, 0, stream>>>(
        Qb, Kb, Sb, lp, nullptr, 2048, 2048, 1024,
        2048L * 1024, 2048L * 1024, 2048L * 2048, 1024, 1024, 2048);

    // 4) linv[r] = 1 / sum of row partial sums
    row_linv<<<dim3(32), dim3(256), 0, stream>>>(lp, linv);

    // 5) O = (P_unnorm @ V) * linv  (A bf16 [2048,2048], B=Vt [1024,2048], f32 out)
    gemm_bt<2><<<dim3(8, 16, 4), 256, 0, stream>>>(
        Sb, Vt, d_out, linv, nullptr, 2048, 1024, 2048,
        2048L * 2048, 1024L * 2048, 2048L * 1024, 2048, 2048, 1024);
}

// Round 9
// 176.023 us; speedup vs baseline: 1.0342x; 1.0342x over previous
//
#include <hip/hip_runtime.h>
#include <hip/hip_bf16.h>
#include <stdint.h>

typedef short bf16x8 __attribute__((ext_vector_type(8)));
typedef float f32x4 __attribute__((ext_vector_type(4)));

__device__ __forceinline__ float b2f(unsigned short u) {
    union { unsigned int i; float f; } c; c.i = ((unsigned int)u) << 16; return c.f;
}
__device__ __forceinline__ unsigned short f2b(float f) {
    union { float f; unsigned int i; } c; c.f = f;
    unsigned int u = c.i;
    u += 0x7fffu + ((u >> 16) & 1u);   // round-to-nearest-even
    return (unsigned short)(u >> 16);
}

__device__ __forceinline__ void gload_lds16(const void* g, void* l) {
    __builtin_amdgcn_global_load_lds(
        (const __attribute__((address_space(1))) void*)g,
        (__attribute__((address_space(3))) void*)l, 16, 0, 0);
}

// ---------------- fused f32 -> bf16 convert: x + Wq + Wk + Wv in one launch ----------------
__global__ __launch_bounds__(256) void convert_all(const float* __restrict__ x,
                                                   const float* __restrict__ Wq,
                                                   const float* __restrict__ Wk,
                                                   const float* __restrict__ Wv,
                                                   unsigned short* __restrict__ xb,
                                                   unsigned short* __restrict__ wb) {
    const long X4 = 2097152, W4 = 262144, TOT = X4 + 3 * W4;
    long i = (long)blockIdx.x * blockDim.x + threadIdx.x;
    long stride = (long)gridDim.x * blockDim.x;
    for (; i < TOT; i += stride) {
        const float4* src;
        ushort4* dst;
        if (i < X4) {
            src = (const float4*)x + i;
            dst = (ushort4*)xb + i;
        } else {
            long j = i - X4;
            int w = (int)(j >> 18);          // 262144 = 2^18
            long off = j & (W4 - 1);
            const float* s = (w == 0) ? Wq : (w == 1) ? Wk : Wv;
            src = (const float4*)s + off;
            dst = (ushort4*)wb + (long)w * W4 + off;
        }
        float4 v = *src;
        ushort4 o;
        o.x = f2b(v.x); o.y = f2b(v.y); o.z = f2b(v.z); o.w = f2b(v.w);
        *dst = o;
    }
}

// ---------------- bf16 transpose: [b][S][D] -> [b][D][S], ushort4 global both sides ----------------
__global__ __launch_bounds__(256) void transpose_bf16(const unsigned short* __restrict__ in,
                                                      unsigned short* __restrict__ out,
                                                      int S, int D) {
    __shared__ unsigned short tile[64][65];
    int d0 = blockIdx.x * 64, s0 = blockIdx.y * 64;
    long base = (long)blockIdx.z * S * D;
    int t = threadIdx.x;
    #pragma unroll
    for (int it = 0; it < 4; it++) {
        int u = it * 256 + t;
        int r = u >> 4, c4 = (u & 15) * 4;
        ushort4 v = *(const ushort4*)&in[base + (long)(s0 + r) * D + d0 + c4];
        tile[r][c4 + 0] = v.x; tile[r][c4 + 1] = v.y;
        tile[r][c4 + 2] = v.z; tile[r][c4 + 3] = v.w;
    }
    __syncthreads();
    #pragma unroll
    for (int it = 0; it < 4; it++) {
        int u = it * 256 + t;
        int rr = u >> 4, c4 = (u & 15) * 4;
        ushort4 o;
        o.x = tile[c4 + 0][rr]; o.y = tile[c4 + 1][rr];
        o.z = tile[c4 + 2][rr]; o.w = tile[c4 + 3][rr];
        *(ushort4*)&out[base + (long)(d0 + rr) * S + s0 + c4] = o;
    }
}

// ---------------- per-row 1/sum reduce: linv[r] = 1 / sum_i lp[i][r] ----------------
// lp layout [32][8192]; row q has ns = ((q>>7)+1)*2 valid slots (written by scores blocks
// nb=0..mb, slots nb*2+wc). Unwritten slots are never read -> no zeroing needed.
__global__ __launch_bounds__(256) void row_linv(const float* __restrict__ lp,
                                                float* __restrict__ linv) {
    int r = blockIdx.x * 256 + threadIdx.x;   // 0..8191 = b*2048 + q
    int q = r & 2047;
    int ns = ((q >> 7) + 1) * 2;
    float s = 0.f;
    for (int i = 0; i < ns; i++) s += lp[i * 8192 + r];
    linv[r] = 1.f / s;
}

// ---------------- bf16 GEMM-BT:  C[m][n] = sum_k A[m][k] * B[n][k] ----------------
// MODE 0: QKV projection. C0/C1/C2 = Q/K/V bf16; Q scaled by 1/32.
// MODE 1: scores. Writes P_unnorm = exp(score) bf16 (masked above diag), row partial
//         sums -> lp (C1). Compact lower-triangular grid (blockIdx.x in [0,136)).
// MODE 2: PV. f32 out scaled by linv[row] (C1), K_eff = min(K, m0+BM).
//         mb = (bz&2) ? 15-y : y so co-resident pairs (b, b+256) balance K-steps.
#define BM 128
#define BN 128
#define BK 64

template <int MODE>
__global__ __launch_bounds__(256)
void gemm_bt(const unsigned short* __restrict__ A, const unsigned short* __restrict__ B,
             void* __restrict__ C0, void* __restrict__ C1, void* __restrict__ C2,
             int M, int N, int K,
             long sA, long sB, long sC, int lda, int ldb, int ldc) {
    int mb, nb;
    if (MODE == 1) {
        // compact lower-triangular decode
        int l = blockIdx.x;
        mb = (int)((sqrtf(8.f * l + 1.f) - 1.f) * 0.5f);
        while ((mb + 1) * (mb + 2) / 2 <= l) mb++;
        while (mb * (mb + 1) / 2 > l) mb--;
        nb = l - mb * (mb + 1) / 2;
    } else if (MODE == 2) {
        // pair-balanced: co-resident blocks (b, b+256) differ in z by 2 -> mb sums to 15
        mb = (blockIdx.z & 2) ? (gridDim.y - 1 - blockIdx.y) : blockIdx.y;
        nb = blockIdx.x;
    } else {
        mb = blockIdx.y;
        nb = blockIdx.x;
    }
    int bz = blockIdx.z;

    __shared__ unsigned short As[BM * BK];
    __shared__ unsigned short Bs[BN * BK];

    const unsigned short* Ab = A + (long)bz * sA;
    const unsigned short* Bb = B + (long)bz * sB;

    const int t = threadIdx.x;
    const int lane = t & 63;
    const int wid = t >> 6;
    const int wr = wid >> 1, wc = wid & 1;
    const int m0 = mb * BM, n0 = nb * BN;

    int Keff = K;
    if (MODE == 2) Keff = min(K, m0 + BM);

    f32x4 acc[4][4];
    #pragma unroll
    for (int i = 0; i < 4; i++)
        #pragma unroll
        for (int j = 0; j < 4; j++) acc[i][j] = (f32x4){0.f, 0.f, 0.f, 0.f};

    // staging map: 16B chunk u = i*256+t; row = u>>3; lds chunk = u&7;
    // source chunk = (u&7) ^ (row&7)  (inverse-XOR-swizzled global source, linear LDS dest)
    int rowS[4], csrc[4];
    #pragma unroll
    for (int i = 0; i < 4; i++) {
        int u = i * 256 + t;
        rowS[i] = u >> 3;
        csrc[i] = (u & 7) ^ (rowS[i] & 7);
    }

    for (int k0 = 0; k0 < Keff; k0 += BK) {
        __syncthreads();   // previous compute done before overwrite
        #pragma unroll
        for (int i = 0; i < 4; i++) {
            const unsigned short* gp = Ab + (long)(m0 + rowS[i]) * lda + k0 + csrc[i] * 8;
            gload_lds16(gp, (void*)&As[(i * 256 + wid * 64) * 8]);
        }
        #pragma unroll
        for (int i = 0; i < 4; i++) {
            const unsigned short* gp = Bb + (long)(n0 + rowS[i]) * ldb + k0 + csrc[i] * 8;
            gload_lds16(gp, (void*)&Bs[(i * 256 + wid * 64) * 8]);
        }
        asm volatile("s_waitcnt vmcnt(0)" ::: "memory");
        __syncthreads();

        #pragma unroll
        for (int s = 0; s < 2; s++) {      // two K=32 slices per BK=64
            bf16x8 af[4], bfr[4];
            int kc = s * 4 + (lane >> 4);  // 16B chunk within row
            #pragma unroll
            for (int m = 0; m < 4; m++) {
                int r = wr * 64 + m * 16 + (lane & 15);
                int c = kc ^ (r & 7);
                af[m] = *(const bf16x8*)&As[r * BK + c * 8];
            }
            #pragma unroll
            for (int n = 0; n < 4; n++) {
                int r = wc * 64 + n * 16 + (lane & 15);
                int c = kc ^ (r & 7);
                bfr[n] = *(const bf16x8*)&Bs[r * BK + c * 8];
            }
            #pragma unroll
            for (int m = 0; m < 4; m++)
                #pragma unroll
                for (int n = 0; n < 4; n++)
                    acc[m][n] = __builtin_amdgcn_mfma_f32_16x16x32_bf16(af[m], bfr[n], acc[m][n], 0, 0, 0);
        }
    }

    // epilogue: C/D layout col=lane&15, row=(lane>>4)*4+reg
    const int r0 = (lane >> 4) * 4;
    const int cf = lane & 15;
    if (MODE == 0) {
        int buf = n0 >> 10;  // which of Q/K/V (BN=128 tiles never straddle 1024)
        unsigned short* Cb = (unsigned short*)(buf == 0 ? C0 : (buf == 1 ? C1 : C2));
        float scale = (buf == 0) ? 0.03125f : 1.0f;  // fold 1/sqrt(1024) into Q
        #pragma unroll
        for (int m = 0; m < 4; m++)
            #pragma unroll
            for (int n = 0; n < 4; n++)
                #pragma unroll
                for (int r = 0; r < 4; r++) {
                    long grow = m0 + wr * 64 + m * 16 + r0 + r;
                    int gcol = (n0 & 1023) + wc * 64 + n * 16 + cf;
                    Cb[grow * 1024 + gcol] = f2b(acc[m][n][r] * scale);
                }
    } else if (MODE == 1) {
        // fused exp + causal mask + per-row partial sums
        unsigned short* Cb = (unsigned short*)C0 + (long)bz * sC;
        float* lp = (float*)C1;   // [32][8192]
        float srow[4][4];
        #pragma unroll
        for (int m = 0; m < 4; m++)
            #pragma unroll
            for (int r = 0; r < 4; r++) srow[m][r] = 0.f;
        #pragma unroll
        for (int m = 0; m < 4; m++)
            #pragma unroll
            for (int n = 0; n < 4; n++)
                #pragma unroll
                for (int r = 0; r < 4; r++) {
                    int grow = m0 + wr * 64 + m * 16 + r0 + r;
                    int gcol = n0 + wc * 64 + n * 16 + cf;
                    float e = (gcol <= grow) ? __expf(acc[m][n][r]) : 0.f;
                    srow[m][r] += e;
                    Cb[(long)grow * ldc + gcol] = f2b(e);
                }
        // reduce across the 16 lanes sharing each row, write slot nb*2+wc
        #pragma unroll
        for (int m = 0; m < 4; m++)
            #pragma unroll
            for (int r = 0; r < 4; r++) {
                float s = srow[m][r];
                s += __shfl_xor(s, 1);
                s += __shfl_xor(s, 2);
                s += __shfl_xor(s, 4);
                s += __shfl_xor(s, 8);
                if ((lane & 15) == 0) {
                    int grow = m0 + wr * 64 + m * 16 + r0 + r;
                    lp[(nb * 2 + wc) * 8192 + bz * 2048 + grow] = s;
                }
            }
    } else {
        float* Cb = (float*)C0 + (long)bz * sC;
        const float* linv = (const float*)C1;   // [4][2048]
        #pragma unroll
        for (int m = 0; m < 4; m++)
            #pragma unroll
            for (int r = 0; r < 4; r++) {
                long grow = m0 + wr * 64 + m * 16 + r0 + r;
                float sc = linv[bz * 2048 + grow];
                #pragma unroll
                for (int n = 0; n < 4; n++) {
                    int gcol = n0 + wc * 64 + n * 16 + cf;
                    Cb[grow * ldc + gcol] = acc[m][n][r] * sc;
                }
            }
    }
}

extern "C" void kernel_launch(void* const* d_in, const int* in_sizes, int n_in,
                              void* d_out, int out_size, void* d_ws, size_t ws_size,
                              hipStream_t stream) {
    const float* x  = (const float*)d_in[0];
    const float* Wq = (const float*)d_in[1];
    const float* Wk = (const float*)d_in[2];
    const float* Wv = (const float*)d_in[3];

    // B=4, S=2048, D=1024. Workspace layout (bytes):
    char* ws = (char*)d_ws;
    unsigned short* xb = (unsigned short*)(ws);                    // 16 MB  [8192][1024]
    unsigned short* wb = (unsigned short*)(ws + 16777216);         // 6 MB   [3072][1024]
    unsigned short* Qb = (unsigned short*)(ws + 23068672);         // 16 MB  [8192][1024] (pre-scaled)
    unsigned short* Kb = (unsigned short*)(ws + 39845888);         // 16 MB
    unsigned short* Vb = (unsigned short*)(ws + 56623104);         // 16 MB  [b][2048][1024]
    unsigned short* Vt = (unsigned short*)(ws + 73400320);         // 16 MB  [b][1024][2048]
    unsigned short* Sb = (unsigned short*)(ws + 90177536);         // 32 MB  [b][2048][2048]
    // lp/linv reuse the xb region (xb is dead after the QKV GEMM; stream-ordered)
    float* lp   = (float*)(ws);                                    // 1 MB   [32][8192]
    float* linv = (float*)(ws + 1048576);                          // 32 KB  [4][2048]

    // 1) convert everything to bf16 in one launch
    convert_all<<<dim3(2048), dim3(256), 0, stream>>>(x, Wq, Wk, Wv, xb, wb);

    // 2) QKV projection: [8192,1024] x [3072,1024]^T  (proven R4/R6 form, 63 us)
    gemm_bt<0><<<dim3(24, 64, 1), 256, 0, stream>>>(
        xb, wb, Qb, Kb, Vb, 8192, 3072, 1024, 0L, 0L, 0L, 1024, 1024, 1024);

    // 3) V -> V^T per batch
    transpose_bf16<<<dim3(16, 32, 4), 256, 0, stream>>>(Vb, Vt, 2048, 1024);

    // 4) P_unnorm = exp(Qs @ K^T) per batch, causal-masked, + row partial sums -> lp
    gemm_bt<1><<<dim3(136, 1, 4), 256, 0, stream>>>(
        Qb, Kb, Sb, lp, nullptr, 2048, 2048, 1024,
        2048L * 1024, 2048L * 1024, 2048L * 2048, 1024, 1024, 2048);

    // 5) linv[r] = 1 / sum of row partial sums
    row_linv<<<dim3(32), dim3(256), 0, stream>>>(lp, linv);

    // 6) O = (P_unnorm @ V) * linv, pair-balanced mb (A bf16 [2048,2048], B=Vt, f32 out)
    gemm_bt<2><<<dim3(8, 16, 4), 256, 0, stream>>>(
        Sb, Vt, d_out, linv, nullptr, 2048, 1024, 2048,
        2048L * 2048, 1024L * 2048, 2048L * 1024, 2048, 2048, 1024);
}

// Round 10
// 168.764 us; speedup vs baseline: 1.0787x; 1.0430x over previous
//
#include <hip/hip_runtime.h>
#include <hip/hip_bf16.h>
#include <stdint.h>

typedef short bf16x8 __attribute__((ext_vector_type(8)));
typedef float f32x4 __attribute__((ext_vector_type(4)));

__device__ __forceinline__ float b2f(unsigned short u) {
    union { unsigned int i; float f; } c; c.i = ((unsigned int)u) << 16; return c.f;
}
__device__ __forceinline__ unsigned short f2b(float f) {
    union { float f; unsigned int i; } c; c.f = f;
    unsigned int u = c.i;
    u += 0x7fffu + ((u >> 16) & 1u);   // round-to-nearest-even
    return (unsigned short)(u >> 16);
}

__device__ __forceinline__ void gload_lds16(const void* g, void* l) {
    __builtin_amdgcn_global_load_lds(
        (const __attribute__((address_space(1))) void*)g,
        (__attribute__((address_space(3))) void*)l, 16, 0, 0);
}

// ---------------- fused f32 -> bf16 convert: x + Wq + Wk + Wv in one launch ----------------
__global__ __launch_bounds__(256) void convert_all(const float* __restrict__ x,
                                                   const float* __restrict__ Wq,
                                                   const float* __restrict__ Wk,
                                                   const float* __restrict__ Wv,
                                                   unsigned short* __restrict__ xb,
                                                   unsigned short* __restrict__ wb) {
    const long X4 = 2097152, W4 = 262144, TOT = X4 + 3 * W4;
    long i = (long)blockIdx.x * blockDim.x + threadIdx.x;
    long stride = (long)gridDim.x * blockDim.x;
    for (; i < TOT; i += stride) {
        const float4* src;
        ushort4* dst;
        if (i < X4) {
            src = (const float4*)x + i;
            dst = (ushort4*)xb + i;
        } else {
            long j = i - X4;
            int w = (int)(j >> 18);          // 262144 = 2^18
            long off = j & (W4 - 1);
            const float* s = (w == 0) ? Wq : (w == 1) ? Wk : Wv;
            src = (const float4*)s + off;
            dst = (ushort4*)wb + (long)w * W4 + off;
        }
        float4 v = *src;
        ushort4 o;
        o.x = f2b(v.x); o.y = f2b(v.y); o.z = f2b(v.z); o.w = f2b(v.w);
        *dst = o;
    }
}

// ---------------- bf16 transpose: [b][S][D] -> [b][D][S], ushort4 global both sides ----------------
__global__ __launch_bounds__(256) void transpose_bf16(const unsigned short* __restrict__ in,
                                                      unsigned short* __restrict__ out,
                                                      int S, int D) {
    __shared__ unsigned short tile[64][65];
    int d0 = blockIdx.x * 64, s0 = blockIdx.y * 64;
    long base = (long)blockIdx.z * S * D;
    int t = threadIdx.x;
    #pragma unroll
    for (int it = 0; it < 4; it++) {
        int u = it * 256 + t;
        int r = u >> 4, c4 = (u & 15) * 4;
        ushort4 v = *(const ushort4*)&in[base + (long)(s0 + r) * D + d0 + c4];
        tile[r][c4 + 0] = v.x; tile[r][c4 + 1] = v.y;
        tile[r][c4 + 2] = v.z; tile[r][c4 + 3] = v.w;
    }
    __syncthreads();
    #pragma unroll
    for (int it = 0; it < 4; it++) {
        int u = it * 256 + t;
        int rr = u >> 4, c4 = (u & 15) * 4;
        ushort4 o;
        o.x = tile[c4 + 0][rr]; o.y = tile[c4 + 1][rr];
        o.z = tile[c4 + 2][rr]; o.w = tile[c4 + 3][rr];
        *(ushort4*)&out[base + (long)(d0 + rr) * S + s0 + c4] = o;
    }
}

// ---------------- per-row 1/sum reduce: linv[r] = 1 / sum_i lp[i][r] ----------------
// lp layout [32][8192]; row q (block-row mq=q>>7) has ns = ceil((mq+1)*4/5)*2 valid slots
// (scores tiles nb=0..ceil((mq+1)*4/5)-1, slots nb*2+wc). Unwritten slots never read.
__global__ __launch_bounds__(256) void row_linv(const float* __restrict__ lp,
                                                float* __restrict__ linv) {
    int r = blockIdx.x * 256 + threadIdx.x;   // 0..8191 = b*2048 + q
    int q = r & 2047;
    int ns = ((((q >> 7) + 1) * 4 + 4) / 5) * 2;
    float s = 0.f;
    for (int i = 0; i < ns; i++) s += lp[i * 8192 + r];
    linv[r] = 1.f / s;
}

// ---------------- bf16 GEMM-BT:  C[m][n] = sum_k A[m][k] * B[n][k] ----------------
// MODE 0: QKV projection. C0/C1/C2 = Q/K/V bf16; Q scaled by 1/32. BN=128.
// MODE 1: scores, BN=160 (one-round grid: 115 tiles/batch, 460 blocks < 512 slots).
//         Writes P_unnorm = exp(score) bf16 (masked above diag, store-guarded at
//         col>=2048), row partial sums -> lp (C1).
// MODE 2: PV. BN=128, f32 out scaled by linv[row] (C1), K_eff = min(K, m0+BM),
//         pair-balanced mb.
#define BM 128
#define BK 64

template <int MODE>
__global__ __launch_bounds__(256)
void gemm_bt(const unsigned short* __restrict__ A, const unsigned short* __restrict__ B,
             void* __restrict__ C0, void* __restrict__ C1, void* __restrict__ C2,
             int M, int N, int K,
             long sA, long sB, long sC, int lda, int ldb, int ldc) {
    constexpr int BNx = (MODE == 1) ? 160 : 128;   // B-tile rows (output cols)
    constexpr int NF  = (MODE == 1) ? 5 : 4;       // n fragments per wave
    constexpr int CHB = BNx * BK / (256 * 8);      // B staging chunks per thread (5 or 4)

    int mb, nb;
    if (MODE == 1) {
        // compact lower-triangular decode over variable row width w(mb)=ceil((mb+1)*4/5)
        int l = blockIdx.x, acc2 = 0;
        mb = 0;
        while (true) {
            int w = ((mb + 1) * 4 + 4) / 5;
            if (l < acc2 + w) { nb = l - acc2; break; }
            acc2 += w; mb++;
        }
    } else if (MODE == 2) {
        // pair-balanced: co-resident blocks (b, b+256) differ in z by 2 -> mb sums to 15
        mb = (blockIdx.z & 2) ? (gridDim.y - 1 - blockIdx.y) : blockIdx.y;
        nb = blockIdx.x;
    } else {
        mb = blockIdx.y;
        nb = blockIdx.x;
    }
    int bz = blockIdx.z;

    __shared__ unsigned short As[BM * BK];
    __shared__ unsigned short Bs[BNx * BK];

    const unsigned short* Ab = A + (long)bz * sA;
    const unsigned short* Bb = B + (long)bz * sB;

    const int t = threadIdx.x;
    const int lane = t & 63;
    const int wid = t >> 6;
    const int wr = wid >> 1, wc = wid & 1;
    const int m0 = mb * BM, n0 = nb * BNx;
    const int nwb = wc * (NF * 16);   // wave n-base: 64 or 80

    int Keff = K;
    if (MODE == 2) Keff = min(K, m0 + BM);

    f32x4 acc[4][NF];
    #pragma unroll
    for (int i = 0; i < 4; i++)
        #pragma unroll
        for (int j = 0; j < NF; j++) acc[i][j] = (f32x4){0.f, 0.f, 0.f, 0.f};

    // staging map: 16B chunk u = i*256+t; row = u>>3; lds chunk = u&7;
    // source chunk = (u&7) ^ (row&7)  (inverse-XOR-swizzled global source, linear LDS dest)
    int rowS[CHB], csrc[CHB];
    #pragma unroll
    for (int i = 0; i < CHB; i++) {
        int u = i * 256 + t;
        rowS[i] = u >> 3;
        csrc[i] = (u & 7) ^ (rowS[i] & 7);
    }

    for (int k0 = 0; k0 < Keff; k0 += BK) {
        __syncthreads();   // previous compute done before overwrite
        #pragma unroll
        for (int i = 0; i < 4; i++) {
            const unsigned short* gp = Ab + (long)(m0 + rowS[i]) * lda + k0 + csrc[i] * 8;
            gload_lds16(gp, (void*)&As[(i * 256 + wid * 64) * 8]);
        }
        #pragma unroll
        for (int i = 0; i < CHB; i++) {
            const unsigned short* gp = Bb + (long)(n0 + rowS[i]) * ldb + k0 + csrc[i] * 8;
            gload_lds16(gp, (void*)&Bs[(i * 256 + wid * 64) * 8]);
        }
        asm volatile("s_waitcnt vmcnt(0)" ::: "memory");
        __syncthreads();

        #pragma unroll
        for (int s = 0; s < 2; s++) {      // two K=32 slices per BK=64
            bf16x8 af[4], bfr[NF];
            int kc = s * 4 + (lane >> 4);  // 16B chunk within row
            #pragma unroll
            for (int m = 0; m < 4; m++) {
                int r = wr * 64 + m * 16 + (lane & 15);
                int c = kc ^ (r & 7);
                af[m] = *(const bf16x8*)&As[r * BK + c * 8];
            }
            #pragma unroll
            for (int n = 0; n < NF; n++) {
                int r = nwb + n * 16 + (lane & 15);
                int c = kc ^ (r & 7);
                bfr[n] = *(const bf16x8*)&Bs[r * BK + c * 8];
            }
            #pragma unroll
            for (int m = 0; m < 4; m++)
                #pragma unroll
                for (int n = 0; n < NF; n++)
                    acc[m][n] = __builtin_amdgcn_mfma_f32_16x16x32_bf16(af[m], bfr[n], acc[m][n], 0, 0, 0);
        }
    }

    // epilogue: C/D layout col=lane&15, row=(lane>>4)*4+reg
    const int r0 = (lane >> 4) * 4;
    const int cf = lane & 15;
    if (MODE == 0) {
        int buf = n0 >> 10;  // which of Q/K/V (BN=128 tiles never straddle 1024)
        unsigned short* Cb = (unsigned short*)(buf == 0 ? C0 : (buf == 1 ? C1 : C2));
        float scale = (buf == 0) ? 0.03125f : 1.0f;  // fold 1/sqrt(1024) into Q
        #pragma unroll
        for (int m = 0; m < 4; m++)
            #pragma unroll
            for (int n = 0; n < NF; n++)
                #pragma unroll
                for (int r = 0; r < 4; r++) {
                    long grow = m0 + wr * 64 + m * 16 + r0 + r;
                    int gcol = (n0 & 1023) + nwb + n * 16 + cf;
                    Cb[grow * 1024 + gcol] = f2b(acc[m][n][r] * scale);
                }
    } else if (MODE == 1) {
        // fused exp + causal mask + per-row partial sums
        unsigned short* Cb = (unsigned short*)C0 + (long)bz * sC;
        float* lp = (float*)C1;   // [32][8192]
        float srow[4][4];
        #pragma unroll
        for (int m = 0; m < 4; m++)
            #pragma unroll
            for (int r = 0; r < 4; r++) srow[m][r] = 0.f;
        #pragma unroll
        for (int m = 0; m < 4; m++)
            #pragma unroll
            for (int n = 0; n < NF; n++)
                #pragma unroll
                for (int r = 0; r < 4; r++) {
                    int grow = m0 + wr * 64 + m * 16 + r0 + r;
                    int gcol = n0 + nwb + n * 16 + cf;
                    float e = (gcol <= grow) ? __expf(acc[m][n][r]) : 0.f;
                    srow[m][r] += e;
                    if (gcol < ldc) Cb[(long)grow * ldc + gcol] = f2b(e);
                }
        // reduce across the 16 lanes sharing each row, write slot nb*2+wc
        #pragma unroll
        for (int m = 0; m < 4; m++)
            #pragma unroll
            for (int r = 0; r < 4; r++) {
                float s = srow[m][r];
                s += __shfl_xor(s, 1);
                s += __shfl_xor(s, 2);
                s += __shfl_xor(s, 4);
                s += __shfl_xor(s, 8);
                if ((lane & 15) == 0) {
                    int grow = m0 + wr * 64 + m * 16 + r0 + r;
                    lp[(nb * 2 + wc) * 8192 + bz * 2048 + grow] = s;
                }
            }
    } else {
        float* Cb = (float*)C0 + (long)bz * sC;
        const float* linv = (const float*)C1;   // [4][2048]
        #pragma unroll
        for (int m = 0; m < 4; m++)
            #pragma unroll
            for (int r = 0; r < 4; r++) {
                long grow = m0 + wr * 64 + m * 16 + r0 + r;
                float sc = linv[bz * 2048 + grow];
                #pragma unroll
                for (int n = 0; n < NF; n++) {
                    int gcol = n0 + nwb + n * 16 + cf;
                    Cb[grow * ldc + gcol] = acc[m][n][r] * sc;
                }
            }
    }
}

extern "C" void kernel_launch(void* const* d_in, const int* in_sizes, int n_in,
                              void* d_out, int out_size, void* d_ws, size_t ws_size,
                              hipStream_t stream) {
    const float* x  = (const float*)d_in[0];
    const float* Wq = (const float*)d_in[1];
    const float* Wk = (const float*)d_in[2];
    const float* Wv = (const float*)d_in[3];

    // B=4, S=2048, D=1024. Workspace layout (bytes):
    char* ws = (char*)d_ws;
    unsigned short* xb = (unsigned short*)(ws);                    // 16 MB  [8192][1024]
    unsigned short* wb = (unsigned short*)(ws + 16777216);         // 6 MB   [3072][1024]
    unsigned short* Qb = (unsigned short*)(ws + 23068672);         // 16 MB  [8192][1024] (pre-scaled)
    unsigned short* Kb = (unsigned short*)(ws + 39845888);         // 16 MB
    unsigned short* Vb = (unsigned short*)(ws + 56623104);         // 16 MB  [b][2048][1024]
    unsigned short* Vt = (unsigned short*)(ws + 73400320);         // 16 MB  [b][1024][2048]
    unsigned short* Sb = (unsigned short*)(ws + 90177536);         // 32 MB  [b][2048][2048]
    // lp/linv reuse the xb region (xb is dead after the QKV GEMM; stream-ordered)
    float* lp   = (float*)(ws);                                    // 1 MB   [32][8192]
    float* linv = (float*)(ws + 1048576);                          // 32 KB  [4][2048]

    // 1) convert everything to bf16 in one launch
    convert_all<<<dim3(2048), dim3(256), 0, stream>>>(x, Wq, Wk, Wv, xb, wb);

    // 2) QKV projection: [8192,1024] x [3072,1024]^T  (proven R4/R6/R9 form, 63 us)
    gemm_bt<0><<<dim3(24, 64, 1), 256, 0, stream>>>(
        xb, wb, Qb, Kb, Vb, 8192, 3072, 1024, 0L, 0L, 0L, 1024, 1024, 1024);

    // 3) V -> V^T per batch
    transpose_bf16<<<dim3(16, 32, 4), 256, 0, stream>>>(Vb, Vt, 2048, 1024);

    // 4) P_unnorm = exp(Qs @ K^T), BN=160 one-round triangular grid (115 tiles/batch)
    gemm_bt<1><<<dim3(115, 1, 4), 256, 0, stream>>>(
        Qb, Kb, Sb, lp, nullptr, 2048, 2048, 1024,
        2048L * 1024, 2048L * 1024, 2048L * 2048, 1024, 1024, 2048);

    // 5) linv[r] = 1 / sum of row partial sums
    row_linv<<<dim3(32), dim3(256), 0, stream>>>(lp, linv);

    // 6) O = (P_unnorm @ V) * linv, pair-balanced mb (A bf16 [2048,2048], B=Vt, f32 out)
    gemm_bt<2><<<dim3(8, 16, 4), 256, 0, stream>>>(
        Sb, Vt, d_out, linv, nullptr, 2048, 1024, 2048,
        2048L * 2048, 1024L * 2048, 2048L * 1024, 2048, 2048, 1024);
}

// Round 11
// 166.224 us; speedup vs baseline: 1.0952x; 1.0153x over previous
//
#include <hip/hip_runtime.h>
#include <hip/hip_bf16.h>
#include <stdint.h>

typedef short bf16x8 __attribute__((ext_vector_type(8)));
typedef float f32x4 __attribute__((ext_vector_type(4)));

__device__ __forceinline__ float b2f(unsigned short u) {
    union { unsigned int i; float f; } c; c.i = ((unsigned int)u) << 16; return c.f;
}
__device__ __forceinline__ unsigned short f2b(float f) {
    union { float f; unsigned int i; } c; c.f = f;
    unsigned int u = c.i;
    u += 0x7fffu + ((u >> 16) & 1u);   // round-to-nearest-even
    return (unsigned short)(u >> 16);
}

__device__ __forceinline__ void gload_lds16(const void* g, void* l) {
    __builtin_amdgcn_global_load_lds(
        (const __attribute__((address_space(1))) void*)g,
        (__attribute__((address_space(3))) void*)l, 16, 0, 0);
}

// ---------------- fused f32 -> bf16 convert: x + Wq + Wk + Wv in one launch ----------------
__global__ __launch_bounds__(256) void convert_all(const float* __restrict__ x,
                                                   const float* __restrict__ Wq,
                                                   const float* __restrict__ Wk,
                                                   const float* __restrict__ Wv,
                                                   unsigned short* __restrict__ xb,
                                                   unsigned short* __restrict__ wb) {
    const long X4 = 2097152, W4 = 262144, TOT = X4 + 3 * W4;
    long i = (long)blockIdx.x * blockDim.x + threadIdx.x;
    long stride = (long)gridDim.x * blockDim.x;
    for (; i < TOT; i += stride) {
        const float4* src;
        ushort4* dst;
        if (i < X4) {
            src = (const float4*)x + i;
            dst = (ushort4*)xb + i;
        } else {
            long j = i - X4;
            int w = (int)(j >> 18);          // 262144 = 2^18
            long off = j & (W4 - 1);
            const float* s = (w == 0) ? Wq : (w == 1) ? Wk : Wv;
            src = (const float4*)s + off;
            dst = (ushort4*)wb + (long)w * W4 + off;
        }
        float4 v = *src;
        ushort4 o;
        o.x = f2b(v.x); o.y = f2b(v.y); o.z = f2b(v.z); o.w = f2b(v.w);
        *dst = o;
    }
}

// ---------------- per-row 1/sum reduce: linv[r] = 1 / sum_i lp[i][r] ----------------
// lp layout [32][8192]; row q (block-row mq=q>>7) has ns = ceil((mq+1)*4/5)*2 valid slots
// (scores tiles nb=0..ceil((mq+1)*4/5)-1, slots nb*2+wc). Unwritten slots never read.
__global__ __launch_bounds__(256) void row_linv(const float* __restrict__ lp,
                                                float* __restrict__ linv) {
    int r = blockIdx.x * 256 + threadIdx.x;   // 0..8191 = b*2048 + q
    int q = r & 2047;
    int ns = ((((q >> 7) + 1) * 4 + 4) / 5) * 2;
    float s = 0.f;
    for (int i = 0; i < ns; i++) s += lp[i * 8192 + r];
    linv[r] = 1.f / s;
}

// ---------------- bf16 GEMM-BT:  C[m][n] = sum_k A[m][k] * B[n][k] ----------------
// MODE 0: QKV projection. C0=Q (scaled 1/32), C1=K row-major; C2=Vt -- V tiles land
//         TRANSPOSED [b][1024][2048] via per-wave LDS bounce (wave-partitioned As/Bs
//         scratch; LDS declarations untouched -> R9/R10 codegen preserved).
// MODE 1: scores, BN=160 (one-round grid: 115 tiles/batch, 460 blocks < 512 slots).
//         Writes P_unnorm = exp(score) bf16 (masked above diag, store-guarded at
//         col>=2048), row partial sums -> lp (C1).
// MODE 2: PV. BN=128, f32 out scaled by linv[row] (C1), K_eff = min(K, m0+BM),
//         pair-balanced mb.
#define BM 128
#define BK 64

template <int MODE>
__global__ __launch_bounds__(256)
void gemm_bt(const unsigned short* __restrict__ A, const unsigned short* __restrict__ B,
             void* __restrict__ C0, void* __restrict__ C1, void* __restrict__ C2,
             int M, int N, int K,
             long sA, long sB, long sC, int lda, int ldb, int ldc) {
    constexpr int BNx = (MODE == 1) ? 160 : 128;   // B-tile rows (output cols)
    constexpr int NF  = (MODE == 1) ? 5 : 4;       // n fragments per wave
    constexpr int CHB = BNx * BK / (256 * 8);      // B staging chunks per thread (5 or 4)

    int mb, nb;
    if (MODE == 1) {
        // compact lower-triangular decode over variable row width w(mb)=ceil((mb+1)*4/5)
        int l = blockIdx.x, acc2 = 0;
        mb = 0;
        while (true) {
            int w = ((mb + 1) * 4 + 4) / 5;
            if (l < acc2 + w) { nb = l - acc2; break; }
            acc2 += w; mb++;
        }
    } else if (MODE == 2) {
        // pair-balanced: co-resident blocks (b, b+256) differ in z by 2 -> mb sums to 15
        mb = (blockIdx.z & 2) ? (gridDim.y - 1 - blockIdx.y) : blockIdx.y;
        nb = blockIdx.x;
    } else {
        mb = blockIdx.y;
        nb = blockIdx.x;
    }
    int bz = blockIdx.z;

    __shared__ unsigned short As[BM * BK];
    __shared__ unsigned short Bs[BNx * BK];

    const unsigned short* Ab = A + (long)bz * sA;
    const unsigned short* Bb = B + (long)bz * sB;

    const int t = threadIdx.x;
    const int lane = t & 63;
    const int wid = t >> 6;
    const int wr = wid >> 1, wc = wid & 1;
    const int m0 = mb * BM, n0 = nb * BNx;
    const int nwb = wc * (NF * 16);   // wave n-base: 64 or 80

    int Keff = K;
    if (MODE == 2) Keff = min(K, m0 + BM);

    f32x4 acc[4][NF];
    #pragma unroll
    for (int i = 0; i < 4; i++)
        #pragma unroll
        for (int j = 0; j < NF; j++) acc[i][j] = (f32x4){0.f, 0.f, 0.f, 0.f};

    // staging map: 16B chunk u = i*256+t; row = u>>3; lds chunk = u&7;
    // source chunk = (u&7) ^ (row&7)  (inverse-XOR-swizzled global source, linear LDS dest)
    int rowS[CHB], csrc[CHB];
    #pragma unroll
    for (int i = 0; i < CHB; i++) {
        int u = i * 256 + t;
        rowS[i] = u >> 3;
        csrc[i] = (u & 7) ^ (rowS[i] & 7);
    }

    for (int k0 = 0; k0 < Keff; k0 += BK) {
        __syncthreads();   // previous compute done before overwrite
        #pragma unroll
        for (int i = 0; i < 4; i++) {
            const unsigned short* gp = Ab + (long)(m0 + rowS[i]) * lda + k0 + csrc[i] * 8;
            gload_lds16(gp, (void*)&As[(i * 256 + wid * 64) * 8]);
        }
        #pragma unroll
        for (int i = 0; i < CHB; i++) {
            const unsigned short* gp = Bb + (long)(n0 + rowS[i]) * ldb + k0 + csrc[i] * 8;
            gload_lds16(gp, (void*)&Bs[(i * 256 + wid * 64) * 8]);
        }
        asm volatile("s_waitcnt vmcnt(0)" ::: "memory");
        __syncthreads();

        #pragma unroll
        for (int s = 0; s < 2; s++) {      // two K=32 slices per BK=64
            bf16x8 af[4], bfr[NF];
            int kc = s * 4 + (lane >> 4);  // 16B chunk within row
            #pragma unroll
            for (int m = 0; m < 4; m++) {
                int r = wr * 64 + m * 16 + (lane & 15);
                int c = kc ^ (r & 7);
                af[m] = *(const bf16x8*)&As[r * BK + c * 8];
            }
            #pragma unroll
            for (int n = 0; n < NF; n++) {
                int r = nwb + n * 16 + (lane & 15);
                int c = kc ^ (r & 7);
                bfr[n] = *(const bf16x8*)&Bs[r * BK + c * 8];
            }
            #pragma unroll
            for (int m = 0; m < 4; m++)
                #pragma unroll
                for (int n = 0; n < NF; n++)
                    acc[m][n] = __builtin_amdgcn_mfma_f32_16x16x32_bf16(af[m], bfr[n], acc[m][n], 0, 0, 0);
        }
    }

    // epilogue: C/D layout col=lane&15, row=(lane>>4)*4+reg
    const int r0 = (lane >> 4) * 4;
    const int cf = lane & 15;
    if (MODE == 0) {
        int buf = n0 >> 10;  // which of Q/K/V (BN=128 tiles never straddle 1024)
        if (buf < 2) {
            unsigned short* Cb = (unsigned short*)(buf == 0 ? C0 : C1);
            float scale = (buf == 0) ? 0.03125f : 1.0f;  // fold 1/sqrt(1024) into Q
            #pragma unroll
            for (int m = 0; m < 4; m++)
                #pragma unroll
                for (int n = 0; n < NF; n++)
                    #pragma unroll
                    for (int r = 0; r < 4; r++) {
                        long grow = m0 + wr * 64 + m * 16 + r0 + r;
                        int gcol = (n0 & 1023) + nwb + n * 16 + cf;
                        Cb[grow * 1024 + gcol] = f2b(acc[m][n][r] * scale);
                    }
        } else {
            // V tile -> Vt[b][1024][2048] via per-wave 64x64 LDS bounce (verified R7).
            // Scratch: wave-partitioned across the EXISTING As/Bs arrays (4096 shorts
            // per wave; MODE 0 has BNx=128 so both arrays hold 8192 shorts).
            __syncthreads();   // all waves done with staging reads
            unsigned short* tw = ((wid < 2) ? As : Bs) + (wid & 1) * 4096;
            #pragma unroll
            for (int m = 0; m < 4; m++)
                #pragma unroll
                for (int n = 0; n < NF; n++) {
                    int dl = n * 16 + cf;                 // d_local 0..63
                    int swz = (dl & 7) << 3;
                    #pragma unroll
                    for (int rp = 0; rp < 2; rp++) {      // pack r pairs -> b32 writes
                        int sl = m * 16 + r0 + rp * 2;    // s_local, even
                        unsigned int pk = (unsigned int)f2b(acc[m][n][rp * 2]) |
                                          ((unsigned int)f2b(acc[m][n][rp * 2 + 1]) << 16);
                        *(unsigned int*)&tw[dl * 64 + (sl ^ swz)] = pk;
                    }
                }
            unsigned short* Vt = (unsigned short*)C2;
            long vbase = ((long)(m0 >> 11) * 1024 + (n0 & 1023) + wc * 64) * 2048
                         + (m0 & 2047) + wr * 64;
            #pragma unroll
            for (int pass = 0; pass < 4; pass++) {
                int rr = (lane >> 2) + pass * 16;     // d_local
                int c8 = (lane & 3) * 16;             // s chunk base
                int swz = (rr & 7) << 3;
                bf16x8 v0 = *(const bf16x8*)&tw[rr * 64 + (c8 ^ swz)];
                bf16x8 v1 = *(const bf16x8*)&tw[rr * 64 + ((c8 + 8) ^ swz)];
                *(bf16x8*)&Vt[vbase + (long)rr * 2048 + c8] = v0;
                *(bf16x8*)&Vt[vbase + (long)rr * 2048 + c8 + 8] = v1;
            }
        }
    } else if (MODE == 1) {
        // fused exp + causal mask + per-row partial sums
        unsigned short* Cb = (unsigned short*)C0 + (long)bz * sC;
        float* lp = (float*)C1;   // [32][8192]
        float srow[4][4];
        #pragma unroll
        for (int m = 0; m < 4; m++)
            #pragma unroll
            for (int r = 0; r < 4; r++) srow[m][r] = 0.f;
        #pragma unroll
        for (int m = 0; m < 4; m++)
            #pragma unroll
            for (int n = 0; n < NF; n++)
                #pragma unroll
                for (int r = 0; r < 4; r++) {
                    int grow = m0 + wr * 64 + m * 16 + r0 + r;
                    int gcol = n0 + nwb + n * 16 + cf;
                    float e = (gcol <= grow) ? __expf(acc[m][n][r]) : 0.f;
                    srow[m][r] += e;
                    if (gcol < ldc) Cb[(long)grow * ldc + gcol] = f2b(e);
                }
        // reduce across the 16 lanes sharing each row, write slot nb*2+wc
        #pragma unroll
        for (int m = 0; m < 4; m++)
            #pragma unroll
            for (int r = 0; r < 4; r++) {
                float s = srow[m][r];
                s += __shfl_xor(s, 1);
                s += __shfl_xor(s, 2);
                s += __shfl_xor(s, 4);
                s += __shfl_xor(s, 8);
                if ((lane & 15) == 0) {
                    int grow = m0 + wr * 64 + m * 16 + r0 + r;
                    lp[(nb * 2 + wc) * 8192 + bz * 2048 + grow] = s;
                }
            }
    } else {
        float* Cb = (float*)C0 + (long)bz * sC;
        const float* linv = (const float*)C1;   // [4][2048]
        #pragma unroll
        for (int m = 0; m < 4; m++)
            #pragma unroll
            for (int r = 0; r < 4; r++) {
                long grow = m0 + wr * 64 + m * 16 + r0 + r;
                float sc = linv[bz * 2048 + grow];
                #pragma unroll
                for (int n = 0; n < NF; n++) {
                    int gcol = n0 + nwb + n * 16 + cf;
                    Cb[grow * ldc + gcol] = acc[m][n][r] * sc;
                }
            }
    }
}

extern "C" void kernel_launch(void* const* d_in, const int* in_sizes, int n_in,
                              void* d_out, int out_size, void* d_ws, size_t ws_size,
                              hipStream_t stream) {
    const float* x  = (const float*)d_in[0];
    const float* Wq = (const float*)d_in[1];
    const float* Wk = (const float*)d_in[2];
    const float* Wv = (const float*)d_in[3];

    // B=4, S=2048, D=1024. Workspace layout (bytes):
    char* ws = (char*)d_ws;
    unsigned short* xb = (unsigned short*)(ws);                    // 16 MB  [8192][1024]
    unsigned short* wb = (unsigned short*)(ws + 16777216);         // 6 MB   [3072][1024]
    unsigned short* Qb = (unsigned short*)(ws + 23068672);         // 16 MB  [8192][1024] (pre-scaled)
    unsigned short* Kb = (unsigned short*)(ws + 39845888);         // 16 MB
    unsigned short* Vt = (unsigned short*)(ws + 73400320);         // 16 MB  [b][1024][2048] (direct)
    unsigned short* Sb = (unsigned short*)(ws + 90177536);         // 32 MB  [b][2048][2048]
    // lp/linv reuse the xb region (xb is dead after the QKV GEMM; stream-ordered)
    float* lp   = (float*)(ws);                                    // 1 MB   [32][8192]
    float* linv = (float*)(ws + 1048576);                          // 32 KB  [4][2048]

    // 1) convert everything to bf16 in one launch
    convert_all<<<dim3(2048), dim3(256), 0, stream>>>(x, Wq, Wk, Wv, xb, wb);

    // 2) QKV projection: [8192,1024] x [3072,1024]^T; V lands transposed in Vt
    gemm_bt<0><<<dim3(24, 64, 1), 256, 0, stream>>>(
        xb, wb, Qb, Kb, Vt, 8192, 3072, 1024, 0L, 0L, 0L, 1024, 1024, 1024);

    // 3) P_unnorm = exp(Qs @ K^T), BN=160 one-round triangular grid (115 tiles/batch)
    gemm_bt<1><<<dim3(115, 1, 4), 256, 0, stream>>>(
        Qb, Kb, Sb, lp, nullptr, 2048, 2048, 1024,
        2048L * 1024, 2048L * 1024, 2048L * 2048, 1024, 1024, 2048);

    // 4) linv[r] = 1 / sum of row partial sums
    row_linv<<<dim3(32), dim3(256), 0, stream>>>(lp, linv);

    // 5) O = (P_unnorm @ V) * linv, pair-balanced mb (A bf16 [2048,2048], B=Vt, f32 out)
    gemm_bt<2><<<dim3(8, 16, 4), 256, 0, stream>>>(
        Sb, Vt, d_out, linv, nullptr, 2048, 1024, 2048,
        2048L * 2048, 1024L * 2048, 2048L * 1024, 2048, 2048, 1024);
}

// Round 12
// 162.365 us; speedup vs baseline: 1.1212x; 1.0238x over previous
//
#include <hip/hip_runtime.h>
#include <hip/hip_bf16.h>
#include <stdint.h>

typedef short bf16x8 __attribute__((ext_vector_type(8)));
typedef float f32x4 __attribute__((ext_vector_type(4)));

__device__ __forceinline__ float b2f(unsigned short u) {
    union { unsigned int i; float f; } c; c.i = ((unsigned int)u) << 16; return c.f;
}
__device__ __forceinline__ unsigned short f2b(float f) {
    union { float f; unsigned int i; } c; c.f = f;
    unsigned int u = c.i;
    u += 0x7fffu + ((u >> 16) & 1u);   // round-to-nearest-even
    return (unsigned short)(u >> 16);
}

__device__ __forceinline__ void gload_lds16(const void* g, void* l) {
    __builtin_amdgcn_global_load_lds(
        (const __attribute__((address_space(1))) void*)g,
        (__attribute__((address_space(3))) void*)l, 16, 0, 0);
}

// ---------------- fused f32 -> bf16 convert: x + Wq + Wk + Wv in one launch ----------------
__global__ __launch_bounds__(256) void convert_all(const float* __restrict__ x,
                                                   const float* __restrict__ Wq,
                                                   const float* __restrict__ Wk,
                                                   const float* __restrict__ Wv,
                                                   unsigned short* __restrict__ xb,
                                                   unsigned short* __restrict__ wb) {
    const long X4 = 2097152, W4 = 262144, TOT = X4 + 3 * W4;
    long i = (long)blockIdx.x * blockDim.x + threadIdx.x;
    long stride = (long)gridDim.x * blockDim.x;
    for (; i < TOT; i += stride) {
        const float4* src;
        ushort4* dst;
        if (i < X4) {
            src = (const float4*)x + i;
            dst = (ushort4*)xb + i;
        } else {
            long j = i - X4;
            int w = (int)(j >> 18);          // 262144 = 2^18
            long off = j & (W4 - 1);
            const float* s = (w == 0) ? Wq : (w == 1) ? Wk : Wv;
            src = (const float4*)s + off;
            dst = (ushort4*)wb + (long)w * W4 + off;
        }
        float4 v = *src;
        ushort4 o;
        o.x = f2b(v.x); o.y = f2b(v.y); o.z = f2b(v.z); o.w = f2b(v.w);
        *dst = o;
    }
}

// ---------------- per-row 1/sum reduce: linv[r] = 1 / sum_i lp[i][r] ----------------
// lp layout [32][8192]; row q (block-row mq=q>>7) has ns = ceil((mq+1)*4/5)*2 valid slots
// (scores tiles nb=0..ceil((mq+1)*4/5)-1, slots nb*2+wc). Unwritten slots never read.
__global__ __launch_bounds__(256) void row_linv(const float* __restrict__ lp,
                                                float* __restrict__ linv) {
    int r = blockIdx.x * 256 + threadIdx.x;   // 0..8191 = b*2048 + q
    int q = r & 2047;
    int ns = ((((q >> 7) + 1) * 4 + 4) / 5) * 2;
    float s = 0.f;
    for (int i = 0; i < ns; i++) s += lp[i * 8192 + r];
    linv[r] = 1.f / s;
}

// ---------------- bf16 GEMM-BT:  C[m][n] = sum_k A[m][k] * B[n][k] ----------------
// MODE 0: QKV projection. C0=Q (scaled 1/32), C1=K row-major; C2=Vt -- V tiles stored
//         TRANSPOSED [b][1024][2048] by direct packed scatter (acc[m][n][0..3] are 4
//         consecutive s at fixed d -> one aligned ushort4 store; no LDS, no barrier).
// MODE 1: scores, BN=160 (one-round grid: 115 tiles/batch, 460 blocks < 512 slots).
//         Writes P_unnorm = exp(score) bf16 (masked above diag, store-guarded at
//         col>=2048), row partial sums -> lp (C1).
// MODE 2: PV. BN=128, f32 out scaled by linv[row] (C1), K_eff = min(K, m0+BM),
//         pair-balanced mb.
#define BM 128
#define BK 64

template <int MODE>
__global__ __launch_bounds__(256)
void gemm_bt(const unsigned short* __restrict__ A, const unsigned short* __restrict__ B,
             void* __restrict__ C0, void* __restrict__ C1, void* __restrict__ C2,
             int M, int N, int K,
             long sA, long sB, long sC, int lda, int ldb, int ldc) {
    constexpr int BNx = (MODE == 1) ? 160 : 128;   // B-tile rows (output cols)
    constexpr int NF  = (MODE == 1) ? 5 : 4;       // n fragments per wave
    constexpr int CHB = BNx * BK / (256 * 8);      // B staging chunks per thread (5 or 4)

    int mb, nb;
    if (MODE == 1) {
        // compact lower-triangular decode over variable row width w(mb)=ceil((mb+1)*4/5)
        int l = blockIdx.x, acc2 = 0;
        mb = 0;
        while (true) {
            int w = ((mb + 1) * 4 + 4) / 5;
            if (l < acc2 + w) { nb = l - acc2; break; }
            acc2 += w; mb++;
        }
    } else if (MODE == 2) {
        // pair-balanced: co-resident blocks (b, b+256) differ in z by 2 -> mb sums to 15
        mb = (blockIdx.z & 2) ? (gridDim.y - 1 - blockIdx.y) : blockIdx.y;
        nb = blockIdx.x;
    } else {
        mb = blockIdx.y;
        nb = blockIdx.x;
    }
    int bz = blockIdx.z;

    __shared__ unsigned short As[BM * BK];
    __shared__ unsigned short Bs[BNx * BK];

    const unsigned short* Ab = A + (long)bz * sA;
    const unsigned short* Bb = B + (long)bz * sB;

    const int t = threadIdx.x;
    const int lane = t & 63;
    const int wid = t >> 6;
    const int wr = wid >> 1, wc = wid & 1;
    const int m0 = mb * BM, n0 = nb * BNx;
    const int nwb = wc * (NF * 16);   // wave n-base: 64 or 80

    int Keff = K;
    if (MODE == 2) Keff = min(K, m0 + BM);

    f32x4 acc[4][NF];
    #pragma unroll
    for (int i = 0; i < 4; i++)
        #pragma unroll
        for (int j = 0; j < NF; j++) acc[i][j] = (f32x4){0.f, 0.f, 0.f, 0.f};

    // staging map: 16B chunk u = i*256+t; row = u>>3; lds chunk = u&7;
    // source chunk = (u&7) ^ (row&7)  (inverse-XOR-swizzled global source, linear LDS dest)
    int rowS[CHB], csrc[CHB];
    #pragma unroll
    for (int i = 0; i < CHB; i++) {
        int u = i * 256 + t;
        rowS[i] = u >> 3;
        csrc[i] = (u & 7) ^ (rowS[i] & 7);
    }

    for (int k0 = 0; k0 < Keff; k0 += BK) {
        __syncthreads();   // previous compute done before overwrite
        #pragma unroll
        for (int i = 0; i < 4; i++) {
            const unsigned short* gp = Ab + (long)(m0 + rowS[i]) * lda + k0 + csrc[i] * 8;
            gload_lds16(gp, (void*)&As[(i * 256 + wid * 64) * 8]);
        }
        #pragma unroll
        for (int i = 0; i < CHB; i++) {
            const unsigned short* gp = Bb + (long)(n0 + rowS[i]) * ldb + k0 + csrc[i] * 8;
            gload_lds16(gp, (void*)&Bs[(i * 256 + wid * 64) * 8]);
        }
        asm volatile("s_waitcnt vmcnt(0)" ::: "memory");
        __syncthreads();

        #pragma unroll
        for (int s = 0; s < 2; s++) {      // two K=32 slices per BK=64
            bf16x8 af[4], bfr[NF];
            int kc = s * 4 + (lane >> 4);  // 16B chunk within row
            #pragma unroll
            for (int m = 0; m < 4; m++) {
                int r = wr * 64 + m * 16 + (lane & 15);
                int c = kc ^ (r & 7);
                af[m] = *(const bf16x8*)&As[r * BK + c * 8];
            }
            #pragma unroll
            for (int n = 0; n < NF; n++) {
                int r = nwb + n * 16 + (lane & 15);
                int c = kc ^ (r & 7);
                bfr[n] = *(const bf16x8*)&Bs[r * BK + c * 8];
            }
            #pragma unroll
            for (int m = 0; m < 4; m++)
                #pragma unroll
                for (int n = 0; n < NF; n++)
                    acc[m][n] = __builtin_amdgcn_mfma_f32_16x16x32_bf16(af[m], bfr[n], acc[m][n], 0, 0, 0);
        }
    }

    // epilogue: C/D layout col=lane&15, row=(lane>>4)*4+reg
    const int r0 = (lane >> 4) * 4;
    const int cf = lane & 15;
    if (MODE == 0) {
        int buf = n0 >> 10;  // which of Q/K/V (BN=128 tiles never straddle 1024)
        if (buf < 2) {
            unsigned short* Cb = (unsigned short*)(buf == 0 ? C0 : C1);
            float scale = (buf == 0) ? 0.03125f : 1.0f;  // fold 1/sqrt(1024) into Q
            #pragma unroll
            for (int m = 0; m < 4; m++)
                #pragma unroll
                for (int n = 0; n < NF; n++)
                    #pragma unroll
                    for (int r = 0; r < 4; r++) {
                        long grow = m0 + wr * 64 + m * 16 + r0 + r;
                        int gcol = (n0 & 1023) + nwb + n * 16 + cf;
                        Cb[grow * 1024 + gcol] = f2b(acc[m][n][r] * scale);
                    }
        } else {
            // V -> Vt[b][1024][2048] direct transposed scatter.
            // acc[m][n][r], r=0..3 = 4 consecutive s at fixed d -> one ushort4 (8B) store.
            unsigned short* Vt = (unsigned short*)C2;
            long vb2 = (long)(m0 >> 11) * 1024 * 2048;   // batch base
            const int sbase = (m0 & 2047) + wr * 64 + r0;
            const int dbase = (n0 & 1023) + nwb + cf;
            #pragma unroll
            for (int m = 0; m < 4; m++)
                #pragma unroll
                for (int n = 0; n < NF; n++) {
                    int d = dbase + n * 16;
                    int s = sbase + m * 16;
                    ushort4 pk;
                    pk.x = f2b(acc[m][n][0]);
                    pk.y = f2b(acc[m][n][1]);
                    pk.z = f2b(acc[m][n][2]);
                    pk.w = f2b(acc[m][n][3]);
                    *(ushort4*)&Vt[vb2 + (long)d * 2048 + s] = pk;
                }
        }
    } else if (MODE == 1) {
        // fused exp + causal mask + per-row partial sums
        unsigned short* Cb = (unsigned short*)C0 + (long)bz * sC;
        float* lp = (float*)C1;   // [32][8192]
        float srow[4][4];
        #pragma unroll
        for (int m = 0; m < 4; m++)
            #pragma unroll
            for (int r = 0; r < 4; r++) srow[m][r] = 0.f;
        #pragma unroll
        for (int m = 0; m < 4; m++)
            #pragma unroll
            for (int n = 0; n < NF; n++)
                #pragma unroll
                for (int r = 0; r < 4; r++) {
                    int grow = m0 + wr * 64 + m * 16 + r0 + r;
                    int gcol = n0 + nwb + n * 16 + cf;
                    float e = (gcol <= grow) ? __expf(acc[m][n][r]) : 0.f;
                    srow[m][r] += e;
                    if (gcol < ldc) Cb[(long)grow * ldc + gcol] = f2b(e);
                }
        // reduce across the 16 lanes sharing each row, write slot nb*2+wc
        #pragma unroll
        for (int m = 0; m < 4; m++)
            #pragma unroll
            for (int r = 0; r < 4; r++) {
                float s = srow[m][r];
                s += __shfl_xor(s, 1);
                s += __shfl_xor(s, 2);
                s += __shfl_xor(s, 4);
                s += __shfl_xor(s, 8);
                if ((lane & 15) == 0) {
                    int grow = m0 + wr * 64 + m * 16 + r0 + r;
                    lp[(nb * 2 + wc) * 8192 + bz * 2048 + grow] = s;
                }
            }
    } else {
        float* Cb = (float*)C0 + (long)bz * sC;
        const float* linv = (const float*)C1;   // [4][2048]
        #pragma unroll
        for (int m = 0; m < 4; m++)
            #pragma unroll
            for (int r = 0; r < 4; r++) {
                long grow = m0 + wr * 64 + m * 16 + r0 + r;
                float sc = linv[bz * 2048 + grow];
                #pragma unroll
                for (int n = 0; n < NF; n++) {
                    int gcol = n0 + nwb + n * 16 + cf;
                    Cb[grow * ldc + gcol] = acc[m][n][r] * sc;
                }
            }
    }
}

extern "C" void kernel_launch(void* const* d_in, const int* in_sizes, int n_in,
                              void* d_out, int out_size, void* d_ws, size_t ws_size,
                              hipStream_t stream) {
    const float* x  = (const float*)d_in[0];
    const float* Wq = (const float*)d_in[1];
    const float* Wk = (const float*)d_in[2];
    const float* Wv = (const float*)d_in[3];

    // B=4, S=2048, D=1024. Workspace layout (bytes):
    char* ws = (char*)d_ws;
    unsigned short* xb = (unsigned short*)(ws);                    // 16 MB  [8192][1024]
    unsigned short* wb = (unsigned short*)(ws + 16777216);         // 6 MB   [3072][1024]
    unsigned short* Qb = (unsigned short*)(ws + 23068672);         // 16 MB  [8192][1024] (pre-scaled)
    unsigned short* Kb = (unsigned short*)(ws + 39845888);         // 16 MB
    unsigned short* Vt = (unsigned short*)(ws + 73400320);         // 16 MB  [b][1024][2048] (direct)
    unsigned short* Sb = (unsigned short*)(ws + 90177536);         // 32 MB  [b][2048][2048]
    // lp/linv reuse the xb region (xb is dead after the QKV GEMM; stream-ordered)
    float* lp   = (float*)(ws);                                    // 1 MB   [32][8192]
    float* linv = (float*)(ws + 1048576);                          // 32 KB  [4][2048]

    // 1) convert everything to bf16 in one launch
    convert_all<<<dim3(2048), dim3(256), 0, stream>>>(x, Wq, Wk, Wv, xb, wb);

    // 2) QKV projection: [8192,1024] x [3072,1024]^T; V lands transposed in Vt
    gemm_bt<0><<<dim3(24, 64, 1), 256, 0, stream>>>(
        xb, wb, Qb, Kb, Vt, 8192, 3072, 1024, 0L, 0L, 0L, 1024, 1024, 1024);

    // 3) P_unnorm = exp(Qs @ K^T), BN=160 one-round triangular grid (115 tiles/batch)
    gemm_bt<1><<<dim3(115, 1, 4), 256, 0, stream>>>(
        Qb, Kb, Sb, lp, nullptr, 2048, 2048, 1024,
        2048L * 1024, 2048L * 1024, 2048L * 2048, 1024, 1024, 2048);

    // 4) linv[r] = 1 / sum of row partial sums
    row_linv<<<dim3(32), dim3(256), 0, stream>>>(lp, linv);

    // 5) O = (P_unnorm @ V) * linv, pair-balanced mb (A bf16 [2048,2048], B=Vt, f32 out)
    gemm_bt<2><<<dim3(8, 16, 4), 256, 0, stream>>>(
        Sb, Vt, d_out, linv, nullptr, 2048, 1024, 2048,
        2048L * 2048, 1024L * 2048, 2048L * 1024, 2048, 2048, 1024);
}